// Round 7
// baseline (546.236 us; speedup 1.0000x reference)
//
#include <hip/hip_runtime.h>
#include <hip/hip_bf16.h>
#include <cstdint>

#define BB 8
#define CC 16
#define DD 32
#define HH 112
#define WW 112
#define TT 16        // D_OUT
#define HID 256
#define OUTN 128
#define INSZ 784     // C*7*7

__device__ __forceinline__ float bf16lo(uint32_t u) { return __uint_as_float(u << 16); }
__device__ __forceinline__ float bf16hi(uint32_t u) { return __uint_as_float(u & 0xffff0000u); }
__device__ __forceinline__ float bf16s(uint16_t u)  { return __uint_as_float(((uint32_t)u) << 16); }

__device__ __forceinline__ uint16_t f32_to_bf16_rne(float f) {
    uint32_t u = __float_as_uint(f);
    return (uint16_t)((u + 0x7fffu + ((u >> 16) & 1u)) >> 16);
}

// ---------------------------------------------------------------------------
// Dtype detector (PROVEN r2/r5/r6): flag=1 -> float32 inputs, 0 -> bfloat16.
// ---------------------------------------------------------------------------
__global__ __launch_bounds__(256) void detect_kernel(const uint16_t* __restrict__ x,
                                                     int* __restrict__ flag) {
    __shared__ int cnt;
    if (threadIdx.x == 0) cnt = 0;
    __syncthreads();
    int local = 0;
    for (int i = threadIdx.x; i < 8192; i += 256) {
        uint32_t e = (x[i] >> 7) & 0xFFu;
        if (e == 0u || e >= 0x90u) local++;
    }
    atomicAdd(&cnt, local);
    __syncthreads();
    if (threadIdx.x == 0) *flag = (cnt > 400) ? 1 : 0;
}

// ---------------------------------------------------------------------------
// Pool (IDENTICAL to r5/r6 PASS): x -> seq (T,B,INSZ) f32, mean over 512.
// ---------------------------------------------------------------------------
__global__ __launch_bounds__(256) void pool_kernel(const void* __restrict__ xv,
                                                   float* __restrict__ seq,
                                                   const int* __restrict__ flag) {
    const int isf32 = *flag;
    int gid = blockIdx.x;                 // 2048 blocks
    int t = gid & 15, c = (gid >> 4) & 15, b = gid >> 8;
    long base = (long)(((b * CC + c) * DD) + t * 2) * (HH * WW);
    __shared__ float chunk[6272];
    int tid = threadIdx.x;
    float s = 0.0f;
    if (!isf32) {
        const uint4* p = reinterpret_cast<const uint4*>((const uint16_t*)xv + base);
        for (int m = tid; m < 3136; m += 256) {
            uint4 v = p[m];
            chunk[m] = bf16lo(v.x) + bf16hi(v.x) + bf16lo(v.y) + bf16hi(v.y)
                     + bf16lo(v.z) + bf16hi(v.z) + bf16lo(v.w) + bf16hi(v.w);
        }
        __syncthreads();
        if (tid < 49) {
            int h2 = tid / 7, w2 = tid - h2 * 7;
            #pragma unroll
            for (int d = 0; d < 2; d++)
                for (int hh = 0; hh < 16; hh++) {
                    int row = d * 1568 + (h2 * 16 + hh) * 14 + w2 * 2;
                    s += chunk[row] + chunk[row + 1];
                }
        }
    } else {
        const float4* p = reinterpret_cast<const float4*>((const float*)xv + base);
        for (int m = tid; m < 6272; m += 256) {
            float4 v = p[m];
            chunk[m] = v.x + v.y + v.z + v.w;
        }
        __syncthreads();
        if (tid < 49) {
            int h2 = tid / 7, w2 = tid - h2 * 7;
            #pragma unroll
            for (int d = 0; d < 2; d++)
                for (int hh = 0; hh < 16; hh++) {
                    int row = d * 3136 + (h2 * 16 + hh) * 28 + w2 * 4;
                    s += chunk[row] + chunk[row + 1] + chunk[row + 2] + chunk[row + 3];
                }
        }
    }
    if (tid < 49) {
        seq[(long)(t * BB + b) * INSZ + c * 49 + tid] = s * (1.0f / 512.0f);
    }
}

// ---------------------------------------------------------------------------
// W_ih -> f32 transposed wihT[k][768].
// ---------------------------------------------------------------------------
__global__ __launch_bounds__(256) void pack_wih(const void* __restrict__ W,
                                                float* __restrict__ WT,
                                                const int* __restrict__ flag) {
    const int isf32 = *flag;
    int g = blockIdx.x * 256 + threadIdx.x;   // 602112 exactly
    int j = g / INSZ, k = g - j * INSZ;
    float v = isf32 ? ((const float*)W)[g] : bf16s(((const uint16_t*)W)[g]);
    WT[(long)k * 768 + j] = v;
}

// ---------------------------------------------------------------------------
// W_hh -> packed bf16 pairs, transposed: whhP[kk][768], kk in [0,128).
// (r6-PROVEN numerics: absmax 4.9e-4 with f32->bf16 quantization)
// ---------------------------------------------------------------------------
__global__ __launch_bounds__(256) void pack_whh(const void* __restrict__ W,
                                                uint32_t* __restrict__ WP,
                                                const int* __restrict__ flag) {
    const int isf32 = *flag;
    int g = blockIdx.x * 256 + threadIdx.x;   // 98304 exactly
    int j = g >> 7, kk = g & 127;
    uint32_t u;
    if (isf32) {
        float2 v = ((const float2*)W)[g];     // W[j][2kk], W[j][2kk+1]
        u = (uint32_t)f32_to_bf16_rne(v.x) | ((uint32_t)f32_to_bf16_rne(v.y) << 16);
    } else {
        u = ((const uint32_t*)W)[g];
    }
    WP[kk * 768 + j] = u;
}

// ---------------------------------------------------------------------------
// gi (IDENTICAL to r6 PASS): 96 blocks = 3 j-groups x 32 tb-groups of 4.
// ---------------------------------------------------------------------------
__global__ __launch_bounds__(256) void gi_kernel(const float* __restrict__ seq,
                                                 const float* __restrict__ wihT,
                                                 const void* __restrict__ bih,
                                                 float* __restrict__ gi,
                                                 const int* __restrict__ flag) {
    const int isf32 = *flag;
    int jg = blockIdx.x % 3, tbg = blockIdx.x / 3;
    int tb0 = tbg * 4;
    int j = jg * 256 + threadIdx.x;
    __shared__ __align__(16) float s_in[INSZ * 4];
    const float* sbase = seq + (long)tb0 * INSZ;
    for (int idx = threadIdx.x; idx < INSZ * 4; idx += 256) {
        int i = idx / INSZ, k = idx - i * INSZ;
        s_in[k * 4 + i] = sbase[idx];
    }
    __syncthreads();
    float bv = isf32 ? ((const float*)bih)[j] : bf16s(((const uint16_t*)bih)[j]);
    float a0 = bv, a1 = bv, a2 = bv, a3 = bv;
    const float* wp = wihT + j;
    const float4* s4 = reinterpret_cast<const float4*>(s_in);
    #pragma unroll 8
    for (int k = 0; k < INSZ; k++) {
        float w = wp[(long)k * 768];
        float4 sv = s4[k];
        a0 += w * sv.x; a1 += w * sv.y; a2 += w * sv.z; a3 += w * sv.w;
    }
    gi[(long)(tb0 + 0) * 768 + j] = a0;
    gi[(long)(tb0 + 1) * 768 + j] = a1;
    gi[(long)(tb0 + 2) * 768 + j] = a2;
    gi[(long)(tb0 + 3) * 768 + j] = a3;
}

// ---------------------------------------------------------------------------
// Sequential GRU. One block/batch, 768 threads. Thread j holds W_hh row j as
// 128 NAMED u32 registers (X-macro -> guaranteed SROA promotion; r6's array
// form spilled to scratch: VGPR_Count=84, 163us). Coalesced one-time load.
// ---------------------------------------------------------------------------
#define F128(X) \
  X(0)X(1)X(2)X(3)X(4)X(5)X(6)X(7)X(8)X(9)X(10)X(11)X(12)X(13)X(14)X(15) \
  X(16)X(17)X(18)X(19)X(20)X(21)X(22)X(23)X(24)X(25)X(26)X(27)X(28)X(29)X(30)X(31) \
  X(32)X(33)X(34)X(35)X(36)X(37)X(38)X(39)X(40)X(41)X(42)X(43)X(44)X(45)X(46)X(47) \
  X(48)X(49)X(50)X(51)X(52)X(53)X(54)X(55)X(56)X(57)X(58)X(59)X(60)X(61)X(62)X(63) \
  X(64)X(65)X(66)X(67)X(68)X(69)X(70)X(71)X(72)X(73)X(74)X(75)X(76)X(77)X(78)X(79) \
  X(80)X(81)X(82)X(83)X(84)X(85)X(86)X(87)X(88)X(89)X(90)X(91)X(92)X(93)X(94)X(95) \
  X(96)X(97)X(98)X(99)X(100)X(101)X(102)X(103)X(104)X(105)X(106)X(107)X(108)X(109)X(110)X(111) \
  X(112)X(113)X(114)X(115)X(116)X(117)X(118)X(119)X(120)X(121)X(122)X(123)X(124)X(125)X(126)X(127)

__global__ __launch_bounds__(768, 3) void gru_kernel(const float* __restrict__ gi,
                                                     const uint32_t* __restrict__ whhP,
                                                     const void* __restrict__ bhh,
                                                     const void* __restrict__ Wout,
                                                     const void* __restrict__ bout,
                                                     void* __restrict__ out,
                                                     const int* __restrict__ flag) {
    const int isf32 = *flag;
    int b = blockIdx.x;
    int j = threadIdx.x;
    __shared__ __align__(16) float h_s[HID];
    __shared__ __align__(16) float g_s[768];
    if (j < HID) h_s[j] = 0.0f;
    float bh = isf32 ? ((const float*)bhh)[j] : bf16s(((const uint16_t*)bhh)[j]);

    const uint32_t* wp = whhP + j;
#define WLOAD(i) const uint32_t w##i = wp[i * 768];
    F128(WLOAD)
#undef WLOAD

    __syncthreads();
    #pragma unroll 1
    for (int t = 0; t < TT; t++) {
        float accx = bh, accy = 0.0f;
        const float2* h2p = reinterpret_cast<const float2*>(h_s);
#define WDOT(i) { float2 hv = h2p[i]; accx += bf16lo(w##i) * hv.x; accy += bf16hi(w##i) * hv.y; }
        F128(WDOT)
#undef WDOT
        g_s[j] = accx + accy;
        __syncthreads();                             // g ready; dots done with h_s
        if (j < HID) {
            const float* gp = gi + (long)(t * BB + b) * 768;
            float r = 1.0f / (1.0f + __expf(-(gp[j]       + g_s[j])));
            float z = 1.0f / (1.0f + __expf(-(gp[j + 256] + g_s[j + 256])));
            float npre = gp[j + 512] + r * g_s[j + 512];
            float n = 2.0f / (1.0f + __expf(-2.0f * npre)) - 1.0f;  // tanh
            h_s[j] = (1.0f - z) * n + z * h_s[j];
        }
        __syncthreads();                             // h ready for next step
    }
    if (j < OUTN) {
        float acc = isf32 ? ((const float*)bout)[j] : bf16s(((const uint16_t*)bout)[j]);
        if (!isf32) {
            const uint4* wo = reinterpret_cast<const uint4*>((const uint16_t*)Wout + (long)j * HID);
            #pragma unroll
            for (int k = 0; k < 32; k++) {
                uint4 v = wo[k];
                const float* hp2 = &h_s[k * 8];
                acc += bf16lo(v.x) * hp2[0] + bf16hi(v.x) * hp2[1]
                     + bf16lo(v.y) * hp2[2] + bf16hi(v.y) * hp2[3]
                     + bf16lo(v.z) * hp2[4] + bf16hi(v.z) * hp2[5]
                     + bf16lo(v.w) * hp2[6] + bf16hi(v.w) * hp2[7];
            }
            ((uint16_t*)out)[b * OUTN + j] = f32_to_bf16_rne(acc);
        } else {
            const float4* wo = reinterpret_cast<const float4*>((const float*)Wout + (long)j * HID);
            #pragma unroll
            for (int k = 0; k < 64; k++) {
                float4 v = wo[k];
                const float* hp2 = &h_s[k * 4];
                acc += v.x * hp2[0] + v.y * hp2[1] + v.z * hp2[2] + v.w * hp2[3];
            }
            ((float*)out)[b * OUTN + j] = acc;
        }
    }
}

extern "C" void kernel_launch(void* const* d_in, const int* in_sizes, int n_in,
                              void* d_out, int out_size, void* d_ws, size_t ws_size,
                              hipStream_t stream) {
    const void* x    = d_in[0];  // 8*16*32*112*112
    const void* Wih  = d_in[1];  // 768*784
    const void* Whh  = d_in[2];  // 768*256
    const void* bih  = d_in[3];  // 768
    const void* bhh  = d_in[4];  // 768
    const void* Wout = d_in[5];  // 128*256
    const void* bout = d_in[6];  // 128

    char* ws = (char*)d_ws;
    float*    seq  = (float*)ws;                  // 401408 B
    float*    gi   = (float*)(ws + 401408);       // 393216 B
    float*    wihT = (float*)(ws + 1048576);      // 2408448 B  [784][768] f32
    uint32_t* whhP = (uint32_t*)(ws + 4194304);   // 393216 B   [128][768] u32
    int*     flagp = (int*)(ws + 8388608);

    detect_kernel<<<1, 256, 0, stream>>>((const uint16_t*)x, flagp);
    pool_kernel<<<2048, 256, 0, stream>>>(x, seq, flagp);
    pack_wih<<<2352, 256, 0, stream>>>(Wih, wihT, flagp);
    pack_whh<<<384, 256, 0, stream>>>(Whh, whhP, flagp);
    gi_kernel<<<96, 256, 0, stream>>>(seq, wihT, bih, gi, flagp);
    gru_kernel<<<8, 768, 0, stream>>>(gi, whhP, bhh, Wout, bout, d_out, flagp);
}